// Round 1
// baseline (132.091 us; speedup 1.0000x reference)
//
#include <hip/hip_runtime.h>
#include <math.h>

// YOLOv1 loss: S=7, B=2, C=1, BATCH=32768
// predictions: (BATCH, 7, 7, 11) fp32   targets: (BATCH, 7, 7, 6) fp32
// out: 5 fp32 scalars: total, coord/bs, conf_obj/bs, conf_noobj/bs, class/bs
//
// v2: coalesced staging. The AoS 44B/24B record stride made every
// global dwordx4 touch ~44 cache lines/wave (2.3x TA amplification,
// measured 2.6 TB/s vs 6.6 TB/s fill ceiling). Now each block stages its
// 1024 contiguous cells into LDS via global_load_lds width=16 (16B/lane,
// perfectly coalesced, async - no VGPR round trip), then computes from
// LDS. Pred LDS reads are stride-11 dwords (coprime 32 -> free 2-way
// alias); tgt stride-6 -> 4-way on a minority of reads (1.58x, minor).
// LDS 69.7KB -> 2 blocks/CU; block B stages while block A computes.

#define PRED_C 11
#define TGT_C  6
#define TPB    256
#define CPT    4                       // cells per thread
#define CPB    (TPB * CPT)             // 1024 cells per block
#define PRED_F (CPB * PRED_C)          // 11264 floats = 45056 B = 11 * 4096
#define TGT_F  (CPB * TGT_C)           //  6144 floats = 24576 B =  6 * 4096
#define LAMBDA_COORD 5.0f
#define LAMBDA_NOOBJ 0.5f
#define EPSV 1e-6f

// fast sigmoid: |rel err| ~1e-6, far inside the absmax budget
__device__ __forceinline__ float fsig(float x) {
    return __builtin_amdgcn_rcpf(1.0f + __expf(-x));
}

// async global->LDS, 16B per lane. LDS dest is wave-uniform base + lane*16
// (hardware-defined); global src is per-lane. Both 16B-aligned here.
__device__ __forceinline__ void gload_lds16(const float* g, float* l) {
    __builtin_amdgcn_global_load_lds(
        (const __attribute__((address_space(1))) void*)g,
        (__attribute__((address_space(3))) void*)l,
        16, 0, 0);
}

// p = 11 floats (box0 x,y,w,h,conf | box1 x,y,w,h,conf | class)
// t = 6 floats  (x,y,w,h,conf,cls)
__device__ __forceinline__ void cell_loss(const float* __restrict__ p,
                                          const float* __restrict__ t,
                                          float& acc_coord, float& acc_cobj,
                                          float& acc_cnoobj, float& acc_cls)
{
    const float tx = t[0], ty = t[1], tw = t[2], th = t[3];
    const float tconf = t[4], tcls = t[5];
    const float obj   = (tconf == 1.0f) ? 1.0f : 0.0f;
    const float noobj = (tconf == 0.0f) ? 1.0f : 0.0f;

    const float t1x = tx - tw * 0.5f, t1y = ty - th * 0.5f;
    const float t2x = tx + tw * 0.5f, t2y = ty + th * 0.5f;
    const float tarea = tw * th;

    const float px[2] = { p[0], p[5] };
    const float py[2] = { p[1], p[6] };
    const float pw[2] = { p[2], p[7] };
    const float ph[2] = { p[3], p[8] };
    const float pf[2] = { p[4], p[9] };

    float iou[2], sx[2], sy[2], aw[2], ah[2], scf[2];
    #pragma unroll
    for (int bb = 0; bb < 2; ++bb) {
        sx[bb]  = fsig(px[bb]);
        sy[bb]  = fsig(py[bb]);
        scf[bb] = fsig(pf[bb]);
        aw[bb]  = fabsf(pw[bb]);
        ah[bb]  = fabsf(ph[bb]);
        const float p1x = sx[bb] - aw[bb] * 0.5f, p1y = sy[bb] - ah[bb] * 0.5f;
        const float p2x = sx[bb] + aw[bb] * 0.5f, p2y = sy[bb] + ah[bb] * 0.5f;
        const float ix = fminf(p2x, t2x) - fmaxf(p1x, t1x);
        const float iy = fminf(p2y, t2y) - fmaxf(p1y, t1y);
        const float inter = fmaxf(ix, 0.0f) * fmaxf(iy, 0.0f);
        const float parea = aw[bb] * ah[bb];
        iou[bb] = inter * __builtin_amdgcn_rcpf(parea + tarea - inter + EPSV);
    }
    // jnp.argmax: first occurrence of max -> box1 only if strictly greater
    const int best = (iou[1] > iou[0]) ? 1 : 0;

    const float dx = sx[best] - tx;
    const float dy = sy[best] - ty;
    const float dw = __builtin_amdgcn_sqrtf(aw[best] + EPSV) -
                     __builtin_amdgcn_sqrtf(tw + EPSV);
    const float dh = __builtin_amdgcn_sqrtf(ah[best] + EPSV) -
                     __builtin_amdgcn_sqrtf(th + EPSV);
    acc_coord += LAMBDA_COORD * obj * ((dx * dx + dy * dy) + (dw * dw + dh * dh));

    const float sc = scf[best];
    acc_cobj += obj * (sc - tconf) * (sc - tconf);

    const float d0 = scf[0] - tconf;
    const float d1 = scf[1] - tconf;
    acc_cnoobj += LAMBDA_NOOBJ * noobj * (d0 * d0 + d1 * d1);

    const float pc = p[10];
    const float bce = fmaxf(pc, 0.0f) - pc * tcls +
                      __logf(1.0f + __expf(-fabsf(pc)));
    acc_cls += obj * bce;
}

__global__ __launch_bounds__(TPB) void yolo_partial_kernel(
    const float* __restrict__ pred,
    const float* __restrict__ tgt,
    float* __restrict__ partials)   // gridDim.x float4s
{
    __shared__ __align__(16) float smem[PRED_F + TGT_F];   // 69632 B
    __shared__ float red[4][4];
    float* spred = smem;
    float* stgt  = smem + PRED_F;

    const int tid  = threadIdx.x;
    const int wave = tid >> 6;
    const int lane = tid & 63;

    // ---- stage: 11 + 6 fully-coalesced async 16B/lane copies ----
    const size_t blk = blockIdx.x;
    const float* gp = pred + blk * (size_t)PRED_F + (size_t)wave * 256 + (size_t)lane * 4;
    const float* gt = tgt  + blk * (size_t)TGT_F  + (size_t)wave * 256 + (size_t)lane * 4;
    float* lp = spred + wave * 256;   // wave-uniform LDS base
    float* lt = stgt  + wave * 256;

    #pragma unroll
    for (int i = 0; i < PRED_C; ++i)
        gload_lds16(gp + i * 1024, lp + i * 1024);
    #pragma unroll
    for (int i = 0; i < TGT_C; ++i)
        gload_lds16(gt + i * 1024, lt + i * 1024);

    asm volatile("s_waitcnt vmcnt(0)" ::: "memory");
    __syncthreads();

    // ---- compute: 4 cells/thread straight out of LDS ----
    float coord = 0.f, cobj = 0.f, cnoobj = 0.f, cls = 0.f;
    #pragma unroll
    for (int k = 0; k < CPT; ++k) {
        const int cell = tid + k * TPB;
        cell_loss(spred + cell * PRED_C, stgt + cell * TGT_C,
                  coord, cobj, cnoobj, cls);
    }

    // ---- reduction: wave shuffle (64-wide) -> cross-wave LDS -> float4 store
    #pragma unroll
    for (int off = 32; off >= 1; off >>= 1) {
        coord  += __shfl_down(coord, off);
        cobj   += __shfl_down(cobj, off);
        cnoobj += __shfl_down(cnoobj, off);
        cls    += __shfl_down(cls, off);
    }
    if (lane == 0) {
        red[wave][0] = coord;
        red[wave][1] = cobj;
        red[wave][2] = cnoobj;
        red[wave][3] = cls;
    }
    __syncthreads();
    if (tid == 0) {
        float4 v;
        v.x = red[0][0] + red[1][0] + red[2][0] + red[3][0];
        v.y = red[0][1] + red[1][1] + red[2][1] + red[3][1];
        v.z = red[0][2] + red[1][2] + red[2][2] + red[3][2];
        v.w = red[0][3] + red[1][3] + red[2][3] + red[3][3];
        ((float4*)partials)[blockIdx.x] = v;
    }
}

__global__ __launch_bounds__(1024) void yolo_final_kernel(
    const float* __restrict__ partials,
    float* __restrict__ out,
    int nblk,
    float inv_bs)
{
    __shared__ float red[16][4];
    const int tid = threadIdx.x;

    float c = 0.f, co = 0.f, cn = 0.f, cl = 0.f;
    for (int i = tid; i < nblk; i += 1024) {
        const float4 v = ((const float4*)partials)[i];
        c += v.x; co += v.y; cn += v.z; cl += v.w;
    }
    #pragma unroll
    for (int off = 32; off >= 1; off >>= 1) {
        c  += __shfl_down(c, off);
        co += __shfl_down(co, off);
        cn += __shfl_down(cn, off);
        cl += __shfl_down(cl, off);
    }
    const int wave = tid >> 6;
    const int lane = tid & 63;
    if (lane == 0) {
        red[wave][0] = c;
        red[wave][1] = co;
        red[wave][2] = cn;
        red[wave][3] = cl;
    }
    __syncthreads();
    if (tid == 0) {
        float sc = 0.f, sco = 0.f, scn = 0.f, scl = 0.f;
        #pragma unroll
        for (int w = 0; w < 16; ++w) {
            sc  += red[w][0];
            sco += red[w][1];
            scn += red[w][2];
            scl += red[w][3];
        }
        out[0] = (sc + sco + scn + scl) * inv_bs;
        out[1] = sc  * inv_bs;
        out[2] = sco * inv_bs;
        out[3] = scn * inv_bs;
        out[4] = scl * inv_bs;
    }
}

extern "C" void kernel_launch(void* const* d_in, const int* in_sizes, int n_in,
                              void* d_out, int out_size, void* d_ws, size_t ws_size,
                              hipStream_t stream) {
    const float* pred = (const float*)d_in[0];
    const float* tgt  = (const float*)d_in[1];
    float* out = (float*)d_out;
    float* partials = (float*)d_ws;

    const long long batch = (long long)in_sizes[0] / (7 * 7 * PRED_C);
    const long long cells = batch * 49;              // 1,605,632
    const int nblk = (int)(cells / CPB);             // 1568 exact

    yolo_partial_kernel<<<nblk, TPB, 0, stream>>>(pred, tgt, partials);
    yolo_final_kernel<<<1, 1024, 0, stream>>>(partials, out, nblk,
                                              1.0f / (float)batch);
}